// Round 1
// baseline (463.788 us; speedup 1.0000x reference)
//
#include <hip/hip_runtime.h>
#include <math.h>

// Problem constants
#define NB   64      // batch
#define NPT  500     // entities == relations per image
#define C1   151     // classes incl. background
#define CM1  150     // kept classes
#define KP   160     // padded K for dot products (zeros in 150..159)
#define TKC  32      // K-chunk staged in LDS
#define LDP  68      // LDS row stride (64 + 4, keeps float4 alignment)

#define SZ_P   ((size_t)NB * NPT * KP)      // 5,120,000 floats per prob tensor
#define SZ_EA  ((size_t)NB * NPT * 8)
#define SZ_RA  ((size_t)NB * NPT * 16)

__device__ __forceinline__ float fdiv_fast(float a, float b) {
    return __fdividef(a, b);
}

// ---------------------------------------------------------------------------
// Kernel 1: one wave (64 lanes) per softmax row. 3 tensors * 64 * 500 = 96000
// rows. Writes fp32 probs (padded to KP with zeros) + per-row aux data.
// entAux[e]: {score, cx_s, cy_s, |p|^2, x0, y0, x1, y1}
// relAux[r]: {rs box x0,y0,x1,y1, ro box x0,y0,x1,y1, vec0..3, rs|p|^2, ro|p|^2, -, -}
// ---------------------------------------------------------------------------
extern "C" __global__ void __launch_bounds__(256)
k_pre(const float* __restrict__ boxes,       // d_in[0]  (B,Ne,4) cxcywh
      const float* __restrict__ ent_logits,  // d_in[1]  (B,Ne,151)
      const float* __restrict__ ro_logits,   // d_in[2]
      const float* __restrict__ rs_logits,   // d_in[3]
      const float* __restrict__ ro_box,      // d_in[4]
      const float* __restrict__ rs_box,      // d_in[5]
      const float* __restrict__ rel_vec,     // d_in[6]
      const float* __restrict__ tsz,         // d_in[7]  (B,2) = [h,w]
      float* __restrict__ entP, float* __restrict__ rsP, float* __restrict__ roP,
      float* __restrict__ entAux, float* __restrict__ relAux)
{
    const int w    = threadIdx.x >> 6;
    const int lane = threadIdx.x & 63;
    const int row  = blockIdx.x * 4 + w;          // 0..95999 (exact)
    const int set  = row / (NB * NPT);            // 0=ent, 1=rs, 2=ro
    const int idx  = row - set * (NB * NPT);
    const int b    = idx / NPT;
    const int i    = idx - b * NPT;

    const float* src = (set == 0 ? ent_logits : (set == 1 ? rs_logits : ro_logits))
                       + (size_t)(b * NPT + i) * C1;

    // --- softmax over 151 classes (lanes cover j = lane, lane+64, lane+128) ---
    const float x0 = src[lane];
    const float x1 = src[lane + 64];
    const float x2 = (lane < C1 - 128) ? src[lane + 128] : -INFINITY;

    float m = fmaxf(fmaxf(x0, x1), x2);
    #pragma unroll
    for (int off = 32; off; off >>= 1) m = fmaxf(m, __shfl_xor(m, off, 64));

    const float e0 = __expf(x0 - m);
    const float e1 = __expf(x1 - m);
    const float e2 = (lane < C1 - 128) ? __expf(x2 - m) : 0.f;
    float s = e0 + e1 + e2;
    #pragma unroll
    for (int off = 32; off; off >>= 1) s += __shfl_xor(s, off, 64);

    const float inv = 1.f / s;
    const float p0 = e0 * inv;            // class j = lane        (<150 always)
    const float p1 = e1 * inv;            // class j = lane+64     (<150 always)
    const float p2 = e2 * inv;            // class j = lane+128

    float* dst = (set == 0 ? entP : (set == 1 ? rsP : roP)) + (size_t)(b * NPT + i) * KP;
    dst[lane]      = p0;
    dst[lane + 64] = p1;
    if (lane + 128 < KP)                   // slots 128..159
        dst[lane + 128] = (lane + 128 < CM1) ? p2 : 0.f;   // class 150 dropped, pad zeros

    // score = max over classes 0..149 ; n2 = sum of squares over 0..149
    float pm = fmaxf(p0, p1);
    float nn = p0 * p0 + p1 * p1;
    if (lane + 128 < CM1) { pm = fmaxf(pm, p2); nn += p2 * p2; }
    #pragma unroll
    for (int off = 32; off; off >>= 1) {
        pm = fmaxf(pm, __shfl_xor(pm, off, 64));
        nn += __shfl_xor(nn, off, 64);
    }

    if (lane == 0) {
        const float hh = tsz[b * 2 + 0];
        const float ww = tsz[b * 2 + 1];
        if (set == 0) {
            const float* bb = boxes + (size_t)(b * NPT + i) * 4;
            const float cx = bb[0], cy = bb[1], bw = bb[2], bh = bb[3];
            const float X0 = (cx - 0.5f * bw) * ww, Y0 = (cy - 0.5f * bh) * hh;
            const float X1 = (cx + 0.5f * bw) * ww, Y1 = (cy + 0.5f * bh) * hh;
            float* A = entAux + (size_t)(b * NPT + i) * 8;
            A[0] = pm;
            A[1] = 0.5f * (X0 + X1);   // scaled center x (matches ref round-trip)
            A[2] = 0.5f * (Y0 + Y1);
            A[3] = nn;
            A[4] = X0; A[5] = Y0; A[6] = X1; A[7] = Y1;
        } else if (set == 1) {
            const float* bb = rs_box  + (size_t)(b * NPT + i) * 4;
            const float* vv = rel_vec + (size_t)(b * NPT + i) * 4;
            const float cx = bb[0], cy = bb[1], bw = bb[2], bh = bb[3];
            float* A = relAux + (size_t)(b * NPT + i) * 16;
            A[0] = (cx - 0.5f * bw) * ww; A[1] = (cy - 0.5f * bh) * hh;
            A[2] = (cx + 0.5f * bw) * ww; A[3] = (cy + 0.5f * bh) * hh;
            A[8]  = vv[0] * ww; A[9]  = vv[1] * hh;
            A[10] = vv[2] * ww; A[11] = vv[3] * hh;
            A[12] = nn;
        } else {
            const float* bb = ro_box + (size_t)(b * NPT + i) * 4;
            const float cx = bb[0], cy = bb[1], bw = bb[2], bh = bb[3];
            float* A = relAux + (size_t)(b * NPT + i) * 16;
            A[4] = (cx - 0.5f * bw) * ww; A[5] = (cy - 0.5f * bh) * hh;
            A[6] = (cx + 0.5f * bw) * ww; A[7] = (cy + 0.5f * bh) * hh;
            A[13] = nn;
        }
    }
}

// ---------------------------------------------------------------------------
// giou (symmetric in a/b), not yet clipped
// ---------------------------------------------------------------------------
__device__ __forceinline__ float giou_c(float ax0, float ay0, float ax1, float ay1,
                                        float bx0, float by0, float bx1, float by1)
{
    const float areaA = (ax1 - ax0) * (ay1 - ay0);
    const float areaB = (bx1 - bx0) * (by1 - by0);
    const float iw = fmaxf(fminf(ax1, bx1) - fmaxf(ax0, bx0), 0.f);
    const float ih = fmaxf(fminf(ay1, by1) - fmaxf(ay0, by0), 0.f);
    const float inter = iw * ih;
    const float uni = areaA + areaB - inter;
    const float cw = fmaxf(ax1, bx1) - fminf(ax0, bx0);
    const float ch = fmaxf(ay1, by1) - fminf(ay0, by0);
    const float areaC = fmaxf(cw, 0.f) * fmaxf(ch, 0.f);
    return fdiv_fast(inter, uni) - fdiv_fast(areaC - uni, areaC);
}

__device__ __forceinline__ float pair_score(float dot, float rn2, float en2,
                                            float score, float dist, float g)
{
    const float d2 = fmaxf(rn2 + en2 - 2.f * dot, 1e-12f);
    const float d  = d2 * __frsqrt_rn(d2);              // sqrt(d2), fast
    const float cls = fdiv_fast(1.f, d + 1.f);
    const float ms  = score * fdiv_fast(1.f, dist + 1.f);
    return ms * cls * fmaxf(g, 0.f);
}

// ---------------------------------------------------------------------------
// Kernel 2: per block, a 64r x 64e tile of one image. Each thread owns a
// 4r x 4e register tile for BOTH matrices (sub & obj). K-loop over KP=160 in
// TKC=32 chunks staged to LDS (transposed [k][row] so compute reads are b128).
// ---------------------------------------------------------------------------
extern "C" __global__ void __launch_bounds__(256)
k_main(const float* __restrict__ entP, const float* __restrict__ rsP,
       const float* __restrict__ roP, const float* __restrict__ eAuxG,
       const float* __restrict__ rAuxG,
       float* __restrict__ outS, float* __restrict__ outO)
{
    __shared__ __align__(16) float sE[TKC][LDP];
    __shared__ __align__(16) float sR[TKC][LDP];
    __shared__ __align__(16) float sO[TKC][LDP];
    __shared__ float eA[64][8];
    __shared__ float rA[64][16];

    const int tid = threadIdx.x;
    const int b   = blockIdx.z;
    const int e0T = blockIdx.x * 64;
    const int r0T = blockIdx.y * 64;

    // aux -> LDS
    for (int t = tid; t < 512; t += 256) {
        const int e = t >> 3, f = t & 7;
        const int ge = e0T + e;
        eA[e][f] = (ge < NPT) ? eAuxG[((size_t)b * NPT + ge) * 8 + f] : 0.f;
    }
    for (int t = tid; t < 1024; t += 256) {
        const int r = t >> 4, f = t & 15;
        const int gr = r0T + r;
        rA[r][f] = (gr < NPT) ? rAuxG[((size_t)b * NPT + gr) * 16 + f] : 0.f;
    }

    float accS[4][4] = {{0.f}}, accO[4][4] = {{0.f}};
    const int eg = tid & 15;   // e-group: columns e0T + eg*4 .. +3
    const int rg = tid >> 4;   // r-group: rows    r0T + rg*4 .. +3

    for (int kc = 0; kc < KP; kc += TKC) {
        __syncthreads();
        // stage chunk, transposed to [k][row]; rows >= 500 zero-filled
        for (int t = tid; t < 64 * TKC; t += 256) {
            const int k = t & (TKC - 1), row = t >> 5;
            const int ge = e0T + row, gr = r0T + row;
            sE[k][row] = (ge < NPT) ? entP[((size_t)b * NPT + ge) * KP + kc + k] : 0.f;
            sR[k][row] = (gr < NPT) ? rsP[((size_t)b * NPT + gr) * KP + kc + k] : 0.f;
            sO[k][row] = (gr < NPT) ? roP[((size_t)b * NPT + gr) * KP + kc + k] : 0.f;
        }
        __syncthreads();
        #pragma unroll 4
        for (int k = 0; k < TKC; ++k) {
            const float4 ev = *(const float4*)&sE[k][eg * 4];
            const float4 sv = *(const float4*)&sR[k][rg * 4];
            const float4 ov = *(const float4*)&sO[k][rg * 4];
            const float evv[4] = {ev.x, ev.y, ev.z, ev.w};
            const float svv[4] = {sv.x, sv.y, sv.z, sv.w};
            const float ovv[4] = {ov.x, ov.y, ov.z, ov.w};
            #pragma unroll
            for (int i = 0; i < 4; ++i) {
                #pragma unroll
                for (int j = 0; j < 4; ++j) {
                    accS[i][j] = fmaf(svv[i], evv[j], accS[i][j]);
                    accO[i][j] = fmaf(ovv[i], evv[j], accO[i][j]);
                }
            }
        }
    }

    // epilogue: fuse giou + center-dist + cls; float4 stores (500 % 4 == 0 so
    // each float4 is fully in-range or fully out)
    const int r0l = rg * 4, e0l = eg * 4;
    const int ge0 = e0T + e0l;
    if (ge0 < NPT) {
        #pragma unroll
        for (int i = 0; i < 4; ++i) {
            const int gr = r0T + r0l + i;
            if (gr >= NPT) continue;
            const float* rr = rA[r0l + i];
            const float rsx0 = rr[0],  rsy0 = rr[1],  rsx1 = rr[2],  rsy1 = rr[3];
            const float rox0 = rr[4],  roy0 = rr[5],  rox1 = rr[6],  roy1 = rr[7];
            const float vsx  = rr[8],  vsy  = rr[9],  vox  = rr[10], voy  = rr[11];
            const float rsn2 = rr[12], ron2 = rr[13];
            float4 vS, vO;
            float* pS = (float*)&vS;
            float* pO = (float*)&vO;
            #pragma unroll
            for (int j = 0; j < 4; ++j) {
                const float* ee = eA[e0l + j];
                const float score = ee[0], ecx = ee[1], ecy = ee[2], en2 = ee[3];
                const float ex0 = ee[4], ey0 = ee[5], ex1 = ee[6], ey1 = ee[7];
                const float gS = giou_c(ex0, ey0, ex1, ey1, rsx0, rsy0, rsx1, rsy1);
                const float gO = giou_c(ex0, ey0, ex1, ey1, rox0, roy0, rox1, roy1);
                const float distS = fabsf(vsx - ecx) + fabsf(vsy - ecy);
                const float distO = fabsf(vox - ecx) + fabsf(voy - ecy);
                pS[j] = pair_score(accS[i][j], rsn2, en2, score, distS, gS);
                pO[j] = pair_score(accO[i][j], ron2, en2, score, distO, gO);
            }
            const size_t o = ((size_t)b * NPT + gr) * NPT + ge0;
            *(float4*)(outS + o) = vS;
            *(float4*)(outO + o) = vO;
        }
    }
}

// ---------------------------------------------------------------------------
extern "C" void kernel_launch(void* const* d_in, const int* in_sizes, int n_in,
                              void* d_out, int out_size, void* d_ws, size_t ws_size,
                              hipStream_t stream)
{
    const float* boxes      = (const float*)d_in[0];
    const float* ent_logits = (const float*)d_in[1];
    const float* ro_logits  = (const float*)d_in[2];
    const float* rs_logits  = (const float*)d_in[3];
    const float* ro_box     = (const float*)d_in[4];
    const float* rs_box     = (const float*)d_in[5];
    const float* rel_vec    = (const float*)d_in[6];
    const float* tsz        = (const float*)d_in[7];

    float* ws   = (float*)d_ws;
    float* entP = ws;
    float* rsP  = ws + SZ_P;
    float* roP  = ws + 2 * SZ_P;
    float* eAux = ws + 3 * SZ_P;
    float* rAux = eAux + SZ_EA;

    float* outS = (float*)d_out;
    float* outO = outS + (size_t)NB * NPT * NPT;

    // 96000 rows / 4 waves per block
    hipLaunchKernelGGL(k_pre, dim3(24000), dim3(256), 0, stream,
                       boxes, ent_logits, ro_logits, rs_logits,
                       ro_box, rs_box, rel_vec, tsz,
                       entP, rsP, roP, eAux, rAux);

    hipLaunchKernelGGL(k_main, dim3(8, 8, NB), dim3(256), 0, stream,
                       entP, rsP, roP, eAux, rAux, outS, outO);
}

// Round 2
// 297.580 us; speedup vs baseline: 1.5585x; 1.5585x over previous
//
#include <hip/hip_runtime.h>
#include <math.h>

// Problem constants
#define NB   64      // batch
#define NPT  500     // entities == relations per image
#define NPTP 512     // row-padded (tiles of 64; rows 500..511 are garbage, discarded)
#define C1   151     // classes incl. background
#define CM1  150     // kept classes
#define KP   160     // padded K (zeros in 150..159)
#define EAF  12      // ent aux floats/row {score,cx,cy,n2, x0,y0,x1,y1, area, pad*3}
#define RAF  20      // rel aux floats/row {rs box*4, ro box*4, vec*4, rsn2, ron2, aRs, aRo, pad*4}

typedef __bf16 bf16x8 __attribute__((ext_vector_type(8)));
typedef float  f32x4  __attribute__((ext_vector_type(4)));

__device__ __forceinline__ float fdiv_fast(float a, float b) { return __fdividef(a, b); }

// ---------------------------------------------------------------------------
// Kernel 1: one wave per softmax row (3*64*500 = 96000 rows).
// Writes bf16 probs padded to KP (rows padded to NPTP, pad rows unwritten ->
// harmless garbage, never stored) + fp32 aux with precomputed areas.
// ---------------------------------------------------------------------------
extern "C" __global__ void __launch_bounds__(256)
k_pre(const float* __restrict__ boxes, const float* __restrict__ ent_logits,
      const float* __restrict__ ro_logits, const float* __restrict__ rs_logits,
      const float* __restrict__ ro_box, const float* __restrict__ rs_box,
      const float* __restrict__ rel_vec, const float* __restrict__ tsz,
      __bf16* __restrict__ entP, __bf16* __restrict__ rsP, __bf16* __restrict__ roP,
      float* __restrict__ entAux, float* __restrict__ relAux)
{
    const int w    = threadIdx.x >> 6;
    const int lane = threadIdx.x & 63;
    const int row  = blockIdx.x * 4 + w;          // 0..95999 exact
    const int set  = row / (NB * NPT);            // 0=ent, 1=rs, 2=ro
    const int idx  = row - set * (NB * NPT);
    const int b    = idx / NPT;
    const int i    = idx - b * NPT;

    const float* src = (set == 0 ? ent_logits : (set == 1 ? rs_logits : ro_logits))
                       + (size_t)(b * NPT + i) * C1;

    const float x0 = src[lane];
    const float x1 = src[lane + 64];
    const float x2 = (lane < C1 - 128) ? src[lane + 128] : -INFINITY;

    float m = fmaxf(fmaxf(x0, x1), x2);
    #pragma unroll
    for (int off = 32; off; off >>= 1) m = fmaxf(m, __shfl_xor(m, off, 64));

    const float e0 = __expf(x0 - m);
    const float e1 = __expf(x1 - m);
    const float e2 = (lane < C1 - 128) ? __expf(x2 - m) : 0.f;
    float s = e0 + e1 + e2;
    #pragma unroll
    for (int off = 32; off; off >>= 1) s += __shfl_xor(s, off, 64);

    const float inv = 1.f / s;
    const float p0 = e0 * inv;
    const float p1 = e1 * inv;
    const float p2 = e2 * inv;

    __bf16* dst = (set == 0 ? entP : (set == 1 ? rsP : roP)) + ((size_t)b * NPTP + i) * KP;
    dst[lane]      = (__bf16)p0;
    dst[lane + 64] = (__bf16)p1;
    if (lane + 128 < KP)
        dst[lane + 128] = (lane + 128 < CM1) ? (__bf16)p2 : (__bf16)0.f;

    // score / |p|^2 over kept classes (fp32 probs, matches reference)
    float pm = fmaxf(p0, p1);
    float nn = p0 * p0 + p1 * p1;
    if (lane + 128 < CM1) { pm = fmaxf(pm, p2); nn += p2 * p2; }
    #pragma unroll
    for (int off = 32; off; off >>= 1) {
        pm = fmaxf(pm, __shfl_xor(pm, off, 64));
        nn += __shfl_xor(nn, off, 64);
    }

    if (lane == 0) {
        const float hh = tsz[b * 2 + 0];
        const float ww = tsz[b * 2 + 1];
        if (set == 0) {
            const float* bb = boxes + (size_t)(b * NPT + i) * 4;
            const float cx = bb[0], cy = bb[1], bw = bb[2], bh = bb[3];
            const float X0 = (cx - 0.5f * bw) * ww, Y0 = (cy - 0.5f * bh) * hh;
            const float X1 = (cx + 0.5f * bw) * ww, Y1 = (cy + 0.5f * bh) * hh;
            float* A = entAux + (size_t)(b * NPT + i) * EAF;
            A[0] = pm;
            A[1] = 0.5f * (X0 + X1);
            A[2] = 0.5f * (Y0 + Y1);
            A[3] = nn;
            A[4] = X0; A[5] = Y0; A[6] = X1; A[7] = Y1;
            A[8] = (X1 - X0) * (Y1 - Y0);
        } else if (set == 1) {
            const float* bb = rs_box  + (size_t)(b * NPT + i) * 4;
            const float* vv = rel_vec + (size_t)(b * NPT + i) * 4;
            const float cx = bb[0], cy = bb[1], bw = bb[2], bh = bb[3];
            float* A = relAux + (size_t)(b * NPT + i) * RAF;
            const float X0 = (cx - 0.5f * bw) * ww, Y0 = (cy - 0.5f * bh) * hh;
            const float X1 = (cx + 0.5f * bw) * ww, Y1 = (cy + 0.5f * bh) * hh;
            A[0] = X0; A[1] = Y0; A[2] = X1; A[3] = Y1;
            A[8]  = vv[0] * ww; A[9]  = vv[1] * hh;
            A[10] = vv[2] * ww; A[11] = vv[3] * hh;
            A[12] = nn;
            A[14] = (X1 - X0) * (Y1 - Y0);
        } else {
            const float* bb = ro_box + (size_t)(b * NPT + i) * 4;
            const float cx = bb[0], cy = bb[1], bw = bb[2], bh = bb[3];
            float* A = relAux + (size_t)(b * NPT + i) * RAF;
            const float X0 = (cx - 0.5f * bw) * ww, Y0 = (cy - 0.5f * bh) * hh;
            const float X1 = (cx + 0.5f * bw) * ww, Y1 = (cy + 0.5f * bh) * hh;
            A[4] = X0; A[5] = Y0; A[6] = X1; A[7] = Y1;
            A[13] = nn;
            A[15] = (X1 - X0) * (Y1 - Y0);
        }
    }
}

// ---------------------------------------------------------------------------
// Kernel 2: 64r x 64e tile per block, 4 waves; wave w owns a 16r x 64e strip.
// MFMA 16x16x32 bf16, fragments loaded straight from global (L2-resident).
// A-frag layout: A[m=lane&15][k=(lane>>4)*8+j]; B[k=(lane>>4)*8+j][n=lane&15];
// C/D: col=lane&15, row=(lane>>4)*4+reg  [learn_hip m89/m91 verified].
// ---------------------------------------------------------------------------
extern "C" __global__ void __launch_bounds__(256, 4)
k_main(const __bf16* __restrict__ entP, const __bf16* __restrict__ rsP,
       const __bf16* __restrict__ roP, const float* __restrict__ eAuxG,
       const float* __restrict__ rAuxG,
       float* __restrict__ outS, float* __restrict__ outO)
{
    __shared__ __align__(16) float eA[64][EAF];   // stride 12 floats: <=2-way banks
    __shared__ __align__(16) float rA[64][RAF];   // stride 20 floats: conflict-free for r%4 pattern

    const int tid = threadIdx.x;
    const int b   = blockIdx.z;
    const int e0T = blockIdx.x * 64;
    const int r0T = blockIdx.y * 64;

    // ---- stage aux to LDS (float4), zero-fill OOB rows ----
    {
        const float4 z = {0.f, 0.f, 0.f, 0.f};
        for (int t = tid; t < 64 * (EAF / 4); t += 256) {
            const int e = t / (EAF / 4), q = t % (EAF / 4);
            const int ge = e0T + e;
            ((float4*)eA[e])[q] = (ge < NPT)
                ? ((const float4*)(eAuxG + ((size_t)b * NPT + ge) * EAF))[q] : z;
        }
        for (int t = tid; t < 64 * (RAF / 4); t += 256) {
            const int r = t / (RAF / 4), q = t % (RAF / 4);
            const int gr = r0T + r;
            ((float4*)rA[r])[q] = (gr < NPT)
                ? ((const float4*)(rAuxG + ((size_t)b * NPT + gr) * RAF))[q] : z;
        }
    }
    __syncthreads();

    const int wv   = tid >> 6;
    const int lane = tid & 63;
    const int lr   = lane & 15;      // A-row / B-col / C-col
    const int kq   = lane >> 4;      // k-quad

    const size_t bOff = (size_t)b * NPTP;
    const __bf16* rsRow = rsP  + (bOff + r0T + wv * 16 + lr) * KP;
    const __bf16* roRow = roP  + (bOff + r0T + wv * 16 + lr) * KP;
    const __bf16* enRow = entP + (bOff + e0T + lr) * KP;

    f32x4 accS[4] = {{0,0,0,0},{0,0,0,0},{0,0,0,0},{0,0,0,0}};
    f32x4 accO[4] = {{0,0,0,0},{0,0,0,0},{0,0,0,0},{0,0,0,0}};

    #pragma unroll
    for (int ks = 0; ks < 5; ++ks) {
        const int ko = ks * 32 + kq * 8;
        const bf16x8 ars = *(const bf16x8*)(rsRow + ko);
        const bf16x8 aro = *(const bf16x8*)(roRow + ko);
        #pragma unroll
        for (int et = 0; et < 4; ++et) {
            const bf16x8 be = *(const bf16x8*)(enRow + (size_t)et * 16 * KP + ko);
            accS[et] = __builtin_amdgcn_mfma_f32_16x16x32_bf16(ars, be, accS[et], 0, 0, 0);
            accO[et] = __builtin_amdgcn_mfma_f32_16x16x32_bf16(aro, be, accO[et], 0, 0, 0);
        }
    }

    // ---- epilogue ----
    f32x4 ev0[4], ev1[4];
    float eArea[4];
    #pragma unroll
    for (int et = 0; et < 4; ++et) {
        const float* ep = eA[et * 16 + lr];
        ev0[et] = *(const f32x4*)(ep);       // score, cx, cy, n2
        ev1[et] = *(const f32x4*)(ep + 4);   // x0, y0, x1, y1
        eArea[et] = ep[8];
    }

    #pragma unroll
    for (int reg = 0; reg < 4; ++reg) {
        const int rIdx = wv * 16 + kq * 4 + reg;
        const int gr   = r0T + rIdx;
        const float* rp = rA[rIdx];
        const f32x4 rsB = *(const f32x4*)(rp);        // rs box
        const f32x4 roB = *(const f32x4*)(rp + 4);    // ro box
        const f32x4 vv  = *(const f32x4*)(rp + 8);    // rel vec (s.x, s.y, o.x, o.y)
        const f32x4 rn  = *(const f32x4*)(rp + 12);   // rsn2, ron2, areaRs, areaRo
        const bool rOK = (gr < NPT);
        const size_t rowOff = ((size_t)b * NPT + gr) * (size_t)NPT;

        #pragma unroll
        for (int et = 0; et < 4; ++et) {
            const int ge = e0T + et * 16 + lr;
            const float score = ev0[et][0], ecx = ev0[et][1], ecy = ev0[et][2], en2 = ev0[et][3];
            const float ex0 = ev1[et][0], ey0 = ev1[et][1], ex1 = ev1[et][2], ey1 = ev1[et][3];
            const float aE = eArea[et];

            // giou vs rs box
            float iwS = fmaxf(fminf(ex1, rsB[2]) - fmaxf(ex0, rsB[0]), 0.f);
            float ihS = fmaxf(fminf(ey1, rsB[3]) - fmaxf(ey0, rsB[1]), 0.f);
            float inS = iwS * ihS;
            float unS = aE + rn[2] - inS;
            float cwS = fmaxf(ex1, rsB[2]) - fminf(ex0, rsB[0]);
            float chS = fmaxf(ey1, rsB[3]) - fminf(ey0, rsB[1]);
            float aCS = cwS * chS;
            float gS  = fmaxf(fdiv_fast(inS, unS) - fdiv_fast(aCS - unS, aCS), 0.f);

            // giou vs ro box
            float iwO = fmaxf(fminf(ex1, roB[2]) - fmaxf(ex0, roB[0]), 0.f);
            float ihO = fmaxf(fminf(ey1, roB[3]) - fmaxf(ey0, roB[1]), 0.f);
            float inO = iwO * ihO;
            float unO = aE + rn[3] - inO;
            float cwO = fmaxf(ex1, roB[2]) - fminf(ex0, roB[0]);
            float chO = fmaxf(ey1, roB[3]) - fminf(ey0, roB[1]);
            float aCO = cwO * chO;
            float gO  = fmaxf(fdiv_fast(inO, unO) - fdiv_fast(aCO - unO, aCO), 0.f);

            // cls + center-dist terms
            const float d2s = fmaxf(rn[0] + en2 - 2.f * accS[et][reg], 1e-12f);
            const float d2o = fmaxf(rn[1] + en2 - 2.f * accO[et][reg], 1e-12f);
            const float dS = d2s * __frsqrt_rn(d2s);
            const float dO = d2o * __frsqrt_rn(d2o);
            const float distS = fabsf(vv[0] - ecx) + fabsf(vv[1] - ecy);
            const float distO = fabsf(vv[2] - ecx) + fabsf(vv[3] - ecy);

            const float vS = score * fdiv_fast(1.f, distS + 1.f) * fdiv_fast(1.f, dS + 1.f) * gS;
            const float vO = score * fdiv_fast(1.f, distO + 1.f) * fdiv_fast(1.f, dO + 1.f) * gO;

            if (rOK && ge < NPT) {
                outS[rowOff + ge] = vS;
                outO[rowOff + ge] = vO;
            }
        }
    }
}

// ---------------------------------------------------------------------------
extern "C" void kernel_launch(void* const* d_in, const int* in_sizes, int n_in,
                              void* d_out, int out_size, void* d_ws, size_t ws_size,
                              hipStream_t stream)
{
    const float* boxes      = (const float*)d_in[0];
    const float* ent_logits = (const float*)d_in[1];
    const float* ro_logits  = (const float*)d_in[2];
    const float* rs_logits  = (const float*)d_in[3];
    const float* ro_box     = (const float*)d_in[4];
    const float* rs_box     = (const float*)d_in[5];
    const float* rel_vec    = (const float*)d_in[6];
    const float* tsz        = (const float*)d_in[7];

    const size_t PROB_ELEMS = (size_t)NB * NPTP * KP;      // 5,242,880 bf16 each
    __bf16* entP = (__bf16*)d_ws;
    __bf16* rsP  = entP + PROB_ELEMS;
    __bf16* roP  = rsP  + PROB_ELEMS;
    float*  eAux = (float*)(roP + PROB_ELEMS);             // byte offset 31.46 MB, 16B-aligned
    float*  rAux = eAux + (size_t)NB * NPT * EAF;

    float* outS = (float*)d_out;
    float* outO = outS + (size_t)NB * NPT * NPT;

    hipLaunchKernelGGL(k_pre, dim3(24000), dim3(256), 0, stream,
                       boxes, ent_logits, ro_logits, rs_logits,
                       ro_box, rs_box, rel_vec, tsz,
                       entP, rsP, roP, eAux, rAux);

    hipLaunchKernelGGL(k_main, dim3(8, 8, NB), dim3(256), 0, stream,
                       entP, rsP, roP, eAux, rAux, outS, outO);
}

// Round 3
// 276.013 us; speedup vs baseline: 1.6803x; 1.0781x over previous
//
#include <hip/hip_runtime.h>
#include <math.h>

// Problem constants
#define NB   64      // batch
#define NPT  500     // entities == relations per image
#define NPTP 512     // row-padded prob tensors (pad rows unwritten garbage, never used for stores)
#define C1   151     // classes incl. background
#define CM1  150     // kept classes
#define KP   160     // padded K (zeros in 150..159)
#define EAF  12      // ent aux floats/row {score,cx,cy,n2, x0,y0,x1,y1, area, pad*3}
#define RAF  20      // rel aux floats/row {rs box*4, ro box*4, vec*4, rsn2, ron2, aRs, aRo, pad*4}

typedef __bf16 bf16x8 __attribute__((ext_vector_type(8)));
typedef float  f32x4  __attribute__((ext_vector_type(4)));

// raw HW transcendentals (v_rcp_f32 / v_rsq_f32, ~1ulp approx — budget is 4.4e-4)
__device__ __forceinline__ float rcpf(float x) { return __builtin_amdgcn_rcpf(x); }
__device__ __forceinline__ float rsqf(float x) { return __builtin_amdgcn_rsqf(x); }

// ---------------------------------------------------------------------------
// Kernel 1: one wave per softmax row (3*64*500 = 96000 rows).
// ---------------------------------------------------------------------------
extern "C" __global__ void __launch_bounds__(256)
k_pre(const float* __restrict__ boxes, const float* __restrict__ ent_logits,
      const float* __restrict__ ro_logits, const float* __restrict__ rs_logits,
      const float* __restrict__ ro_box, const float* __restrict__ rs_box,
      const float* __restrict__ rel_vec, const float* __restrict__ tsz,
      __bf16* __restrict__ entP, __bf16* __restrict__ rsP, __bf16* __restrict__ roP,
      float* __restrict__ entAux, float* __restrict__ relAux)
{
    const int w    = threadIdx.x >> 6;
    const int lane = threadIdx.x & 63;
    const int row  = blockIdx.x * 4 + w;          // 0..95999 exact
    const int set  = row / (NB * NPT);            // 0=ent, 1=rs, 2=ro
    const int idx  = row - set * (NB * NPT);
    const int b    = idx / NPT;
    const int i    = idx - b * NPT;

    const float* src = (set == 0 ? ent_logits : (set == 1 ? rs_logits : ro_logits))
                       + (size_t)(b * NPT + i) * C1;

    const float x0 = src[lane];
    const float x1 = src[lane + 64];
    const float x2 = (lane < C1 - 128) ? src[lane + 128] : -INFINITY;

    float m = fmaxf(fmaxf(x0, x1), x2);
    #pragma unroll
    for (int off = 32; off; off >>= 1) m = fmaxf(m, __shfl_xor(m, off, 64));

    const float e0 = __expf(x0 - m);
    const float e1 = __expf(x1 - m);
    const float e2 = (lane < C1 - 128) ? __expf(x2 - m) : 0.f;
    float s = e0 + e1 + e2;
    #pragma unroll
    for (int off = 32; off; off >>= 1) s += __shfl_xor(s, off, 64);

    const float inv = 1.f / s;
    const float p0 = e0 * inv;
    const float p1 = e1 * inv;
    const float p2 = e2 * inv;

    __bf16* dst = (set == 0 ? entP : (set == 1 ? rsP : roP)) + ((size_t)b * NPTP + i) * KP;
    dst[lane]      = (__bf16)p0;
    dst[lane + 64] = (__bf16)p1;
    if (lane + 128 < KP)
        dst[lane + 128] = (lane + 128 < CM1) ? (__bf16)p2 : (__bf16)0.f;

    float pm = fmaxf(p0, p1);
    float nn = p0 * p0 + p1 * p1;
    if (lane + 128 < CM1) { pm = fmaxf(pm, p2); nn += p2 * p2; }
    #pragma unroll
    for (int off = 32; off; off >>= 1) {
        pm = fmaxf(pm, __shfl_xor(pm, off, 64));
        nn += __shfl_xor(nn, off, 64);
    }

    if (lane == 0) {
        const float hh = tsz[b * 2 + 0];
        const float ww = tsz[b * 2 + 1];
        if (set == 0) {
            const float* bb = boxes + (size_t)(b * NPT + i) * 4;
            const float cx = bb[0], cy = bb[1], bw = bb[2], bh = bb[3];
            const float X0 = (cx - 0.5f * bw) * ww, Y0 = (cy - 0.5f * bh) * hh;
            const float X1 = (cx + 0.5f * bw) * ww, Y1 = (cy + 0.5f * bh) * hh;
            float* A = entAux + (size_t)(b * NPT + i) * EAF;
            A[0] = pm;
            A[1] = 0.5f * (X0 + X1);
            A[2] = 0.5f * (Y0 + Y1);
            A[3] = nn;
            A[4] = X0; A[5] = Y0; A[6] = X1; A[7] = Y1;
            A[8] = (X1 - X0) * (Y1 - Y0);
        } else if (set == 1) {
            const float* bb = rs_box  + (size_t)(b * NPT + i) * 4;
            const float* vv = rel_vec + (size_t)(b * NPT + i) * 4;
            const float cx = bb[0], cy = bb[1], bw = bb[2], bh = bb[3];
            float* A = relAux + (size_t)(b * NPT + i) * RAF;
            const float X0 = (cx - 0.5f * bw) * ww, Y0 = (cy - 0.5f * bh) * hh;
            const float X1 = (cx + 0.5f * bw) * ww, Y1 = (cy + 0.5f * bh) * hh;
            A[0] = X0; A[1] = Y0; A[2] = X1; A[3] = Y1;
            A[8]  = vv[0] * ww; A[9]  = vv[1] * hh;
            A[10] = vv[2] * ww; A[11] = vv[3] * hh;
            A[12] = nn;
            A[14] = (X1 - X0) * (Y1 - Y0);
        } else {
            const float* bb = ro_box + (size_t)(b * NPT + i) * 4;
            const float cx = bb[0], cy = bb[1], bw = bb[2], bh = bb[3];
            float* A = relAux + (size_t)(b * NPT + i) * RAF;
            const float X0 = (cx - 0.5f * bw) * ww, Y0 = (cy - 0.5f * bh) * hh;
            const float X1 = (cx + 0.5f * bw) * ww, Y1 = (cy + 0.5f * bh) * hh;
            A[4] = X0; A[5] = Y0; A[6] = X1; A[7] = Y1;
            A[13] = nn;
            A[15] = (X1 - X0) * (Y1 - Y0);
        }
    }
}

// ---------------------------------------------------------------------------
// Epilogue, templated on FULL (no bounds checks when the 64x64 tile is fully
// in-range — true for 49/64 blocks).
// g = clip(inter/uni - (areaC-uni)/areaC) rewritten as inter*rcp(uni) +
// uni*rcp(areaC) - 1 (algebraically identical).
// ---------------------------------------------------------------------------
template <bool FULL>
__device__ __forceinline__ void epilogue(
    const float (*eA)[EAF], const float (*rA)[RAF],
    const f32x4* accS, const f32x4* accO,
    int lr, int kq, int wv, int b, int e0T, int r0T,
    float* __restrict__ outS, float* __restrict__ outO)
{
    f32x4 ev0[4], ev1[4];
    float eArea[4];
    #pragma unroll
    for (int et = 0; et < 4; ++et) {
        const float* ep = eA[et * 16 + lr];
        ev0[et] = *(const f32x4*)(ep);       // score, cx, cy, n2
        ev1[et] = *(const f32x4*)(ep + 4);   // x0, y0, x1, y1
        eArea[et] = ep[8];
    }

    // 32-bit element offsets: max 64*500*500 = 16M < 2^31
    const unsigned baseR0 = ((unsigned)b * NPT + (unsigned)(r0T + wv * 16 + kq * 4)) * NPT;
    const unsigned eBase  = (unsigned)(e0T + lr);

    #pragma unroll
    for (int reg = 0; reg < 4; ++reg) {
        const int rIdx = wv * 16 + kq * 4 + reg;
        const bool rOK = FULL || (r0T + rIdx < NPT);
        const float* rp = rA[rIdx];
        const f32x4 rsB = *(const f32x4*)(rp);        // rs box
        const f32x4 roB = *(const f32x4*)(rp + 4);    // ro box
        const f32x4 vv  = *(const f32x4*)(rp + 8);    // vec: sx, sy, ox, oy
        const f32x4 rn  = *(const f32x4*)(rp + 12);   // rsn2, ron2, areaRs, areaRo
        const unsigned rowOff = baseR0 + (unsigned)reg * NPT;

        #pragma unroll
        for (int et = 0; et < 4; ++et) {
            const float score = ev0[et][0], ecx = ev0[et][1], ecy = ev0[et][2], en2 = ev0[et][3];
            const float ex0 = ev1[et][0], ey0 = ev1[et][1], ex1 = ev1[et][2], ey1 = ev1[et][3];
            const float aE = eArea[et];

            // giou vs rs
            const float iwS = fmaxf(fminf(ex1, rsB[2]) - fmaxf(ex0, rsB[0]), 0.f);
            const float ihS = fmaxf(fminf(ey1, rsB[3]) - fmaxf(ey0, rsB[1]), 0.f);
            const float inS = iwS * ihS;
            const float unS = aE + rn[2] - inS;
            const float aCS = (fmaxf(ex1, rsB[2]) - fminf(ex0, rsB[0]))
                            * (fmaxf(ey1, rsB[3]) - fminf(ey0, rsB[1]));
            const float gS  = fmaxf(fmaf(inS, rcpf(unS), fmaf(unS, rcpf(aCS), -1.f)), 0.f);

            // giou vs ro
            const float iwO = fmaxf(fminf(ex1, roB[2]) - fmaxf(ex0, roB[0]), 0.f);
            const float ihO = fmaxf(fminf(ey1, roB[3]) - fmaxf(ey0, roB[1]), 0.f);
            const float inO = iwO * ihO;
            const float unO = aE + rn[3] - inO;
            const float aCO = (fmaxf(ex1, roB[2]) - fminf(ex0, roB[0]))
                            * (fmaxf(ey1, roB[3]) - fminf(ey0, roB[1]));
            const float gO  = fmaxf(fmaf(inO, rcpf(unO), fmaf(unO, rcpf(aCO), -1.f)), 0.f);

            // cls distance (sqrt via x*rsq(x)) + L1 center distance, folded rcp
            const float d2s = fmaxf(fmaf(-2.f, accS[et][reg], rn[0] + en2), 1e-12f);
            const float d2o = fmaxf(fmaf(-2.f, accO[et][reg], rn[1] + en2), 1e-12f);
            const float dS  = d2s * rsqf(d2s);
            const float dO  = d2o * rsqf(d2o);
            const float distS = fabsf(vv[0] - ecx) + fabsf(vv[1] - ecy);
            const float distO = fabsf(vv[2] - ecx) + fabsf(vv[3] - ecy);
            const float qS = rcpf((distS + 1.f) * (dS + 1.f));
            const float qO = rcpf((distO + 1.f) * (dO + 1.f));

            const float vS = score * qS * gS;
            const float vO = score * qO * gO;

            const unsigned o = rowOff + eBase + (unsigned)(et * 16);
            if (FULL || (rOK && (int)(eBase + et * 16) < NPT)) {
                outS[o] = vS;
                outO[o] = vO;
            }
        }
    }
}

// ---------------------------------------------------------------------------
// Kernel 2: 64r x 64e tile per block, 4 waves; wave owns 16r x 64e strip.
// MFMA 16x16x32 bf16, fragments straight from global (L2-resident).
// ---------------------------------------------------------------------------
extern "C" __global__ void __launch_bounds__(256, 4)
k_main(const __bf16* __restrict__ entP, const __bf16* __restrict__ rsP,
       const __bf16* __restrict__ roP, const float* __restrict__ eAuxG,
       const float* __restrict__ rAuxG,
       float* __restrict__ outS, float* __restrict__ outO)
{
    __shared__ __align__(16) float eA[64][EAF];
    __shared__ __align__(16) float rA[64][RAF];

    const int tid = threadIdx.x;
    const int b   = blockIdx.z;
    const int e0T = blockIdx.x * 64;
    const int r0T = blockIdx.y * 64;

    {
        const float4 z = {0.f, 0.f, 0.f, 0.f};
        for (int t = tid; t < 64 * (EAF / 4); t += 256) {
            const int e = t / (EAF / 4), q = t % (EAF / 4);
            const int ge = e0T + e;
            ((float4*)eA[e])[q] = (ge < NPT)
                ? ((const float4*)(eAuxG + ((size_t)b * NPT + ge) * EAF))[q] : z;
        }
        for (int t = tid; t < 64 * (RAF / 4); t += 256) {
            const int r = t / (RAF / 4), q = t % (RAF / 4);
            const int gr = r0T + r;
            ((float4*)rA[r])[q] = (gr < NPT)
                ? ((const float4*)(rAuxG + ((size_t)b * NPT + gr) * RAF))[q] : z;
        }
    }
    __syncthreads();

    const int wv   = tid >> 6;
    const int lane = tid & 63;
    const int lr   = lane & 15;      // A-row / B-col / C-col
    const int kq   = lane >> 4;      // k-quad

    const size_t bOff = (size_t)b * NPTP;
    const __bf16* rsRow = rsP  + (bOff + r0T + wv * 16 + lr) * KP;
    const __bf16* roRow = roP  + (bOff + r0T + wv * 16 + lr) * KP;
    const __bf16* enRow = entP + (bOff + e0T + lr) * KP;

    f32x4 accS[4] = {{0,0,0,0},{0,0,0,0},{0,0,0,0},{0,0,0,0}};
    f32x4 accO[4] = {{0,0,0,0},{0,0,0,0},{0,0,0,0},{0,0,0,0}};

    #pragma unroll
    for (int ks = 0; ks < 5; ++ks) {
        const int ko = ks * 32 + kq * 8;
        const bf16x8 ars = *(const bf16x8*)(rsRow + ko);
        const bf16x8 aro = *(const bf16x8*)(roRow + ko);
        #pragma unroll
        for (int et = 0; et < 4; ++et) {
            const bf16x8 be = *(const bf16x8*)(enRow + (size_t)et * 16 * KP + ko);
            accS[et] = __builtin_amdgcn_mfma_f32_16x16x32_bf16(ars, be, accS[et], 0, 0, 0);
            accO[et] = __builtin_amdgcn_mfma_f32_16x16x32_bf16(aro, be, accO[et], 0, 0, 0);
        }
    }

    if (e0T + 64 <= NPT && r0T + 64 <= NPT) {
        epilogue<true >(eA, rA, accS, accO, lr, kq, wv, b, e0T, r0T, outS, outO);
    } else {
        epilogue<false>(eA, rA, accS, accO, lr, kq, wv, b, e0T, r0T, outS, outO);
    }
}

// ---------------------------------------------------------------------------
extern "C" void kernel_launch(void* const* d_in, const int* in_sizes, int n_in,
                              void* d_out, int out_size, void* d_ws, size_t ws_size,
                              hipStream_t stream)
{
    const float* boxes      = (const float*)d_in[0];
    const float* ent_logits = (const float*)d_in[1];
    const float* ro_logits  = (const float*)d_in[2];
    const float* rs_logits  = (const float*)d_in[3];
    const float* ro_box     = (const float*)d_in[4];
    const float* rs_box     = (const float*)d_in[5];
    const float* rel_vec    = (const float*)d_in[6];
    const float* tsz        = (const float*)d_in[7];

    const size_t PROB_ELEMS = (size_t)NB * NPTP * KP;
    __bf16* entP = (__bf16*)d_ws;
    __bf16* rsP  = entP + PROB_ELEMS;
    __bf16* roP  = rsP  + PROB_ELEMS;
    float*  eAux = (float*)(roP + PROB_ELEMS);
    float*  rAux = eAux + (size_t)NB * NPT * EAF;

    float* outS = (float*)d_out;
    float* outO = outS + (size_t)NB * NPT * NPT;

    hipLaunchKernelGGL(k_pre, dim3(24000), dim3(256), 0, stream,
                       boxes, ent_logits, ro_logits, rs_logits,
                       ro_box, rs_box, rel_vec, tsz,
                       entP, rsP, roP, eAux, rAux);

    hipLaunchKernelGGL(k_main, dim3(8, 8, NB), dim3(256), 0, stream,
                       entP, rsP, roP, eAux, rAux, outS, outO);
}

// Round 4
// 235.708 us; speedup vs baseline: 1.9676x; 1.1710x over previous
//
#include <hip/hip_runtime.h>
#include <math.h>

// Problem constants
#define NB   64      // batch
#define NPT  500     // entities == relations per image
#define C1   151     // classes incl. background
#define CM1  150     // kept classes
#define EAF  12      // ent aux floats/row {score,cx,cy,n2, x0,y0,x1,y1, area, pad*3}
#define RAF  20      // rel aux floats/row {rs box*4, ro box*4, vec*4, rsn2, ron2, aRs, aRo, pad*4}

// Swizzled prob layout (bf16): [img][g=row/16][kb=k/8][ir=row%16][8]
//   per group: 20 kb * 16 rows * 8 = 2560 elems (5120 B)
//   per image: 32 groups = 81920 elems (163840 B)
// => every MFMA fragment load (16 rows x 8 k per quarter-wave, 4 kq) is a
//    contiguous 1 KB wave read.
#define GRP_ELEMS  2560
#define IMG_ELEMS  (32 * GRP_ELEMS)
#define PROB_ELEMS ((size_t)NB * IMG_ELEMS)

typedef __bf16 bf16x8 __attribute__((ext_vector_type(8)));
typedef float  f32x4  __attribute__((ext_vector_type(4)));

__device__ __forceinline__ float rcpf(float x) { return __builtin_amdgcn_rcpf(x); }
__device__ __forceinline__ float rsqf(float x) { return __builtin_amdgcn_rsqf(x); }

// ---------------------------------------------------------------------------
// Kernel 1: 16 lanes per row, 16 rows per 256-thread block.
// Grid: 3 sets * 2000 blocks. Fused reductions: {m_all, m_kept} then {s, s2}.
// pm = exp(m_kept - m_all) / s  (no third reduction).
// Probs stored bf16 in swizzled layout; k slots for class 150 and 151..159 = 0.
// ---------------------------------------------------------------------------
extern "C" __global__ void __launch_bounds__(256)
k_pre(const float* __restrict__ boxes, const float* __restrict__ ent_logits,
      const float* __restrict__ ro_logits, const float* __restrict__ rs_logits,
      const float* __restrict__ ro_box, const float* __restrict__ rs_box,
      const float* __restrict__ rel_vec, const float* __restrict__ tsz,
      __bf16* __restrict__ entP, __bf16* __restrict__ rsP, __bf16* __restrict__ roP,
      float* __restrict__ entAux, float* __restrict__ relAux)
{
    const int tid = threadIdx.x;
    const int q   = tid & 15;                 // lane within row
    const int rl  = tid >> 4;                 // row within block (0..15)
    const int bx  = blockIdx.x;
    const int set = bx / 2000;                // 0=ent, 1=rs, 2=ro
    const int rowIdx = (bx - set * 2000) * 16 + rl;   // 0..31999 == b*500+i
    const int b = rowIdx / 500;
    const int i = rowIdx - b * 500;

    const float* src = (set == 0 ? ent_logits : (set == 1 ? rs_logits : ro_logits))
                       + (size_t)rowIdx * C1;

    // elements j = q + 16t, t=0..9 (t=9 valid only for q<=6, j<=150)
    float x[10];
    #pragma unroll
    for (int t = 0; t < 9; ++t) x[t] = src[q + 16 * t];
    x[9] = (q <= 6) ? src[q + 144] : -INFINITY;

    float mAll = x[0];
    #pragma unroll
    for (int t = 1; t < 10; ++t) mAll = fmaxf(mAll, x[t]);
    float mKept = x[0];
    #pragma unroll
    for (int t = 1; t < 9; ++t) mKept = fmaxf(mKept, x[t]);
    if (q <= 5) mKept = fmaxf(mKept, x[9]);   // j=150 (q==6) excluded from kept

    #pragma unroll
    for (int off = 1; off < 16; off <<= 1) {
        mAll  = fmaxf(mAll,  __shfl_xor(mAll,  off, 16));
        mKept = fmaxf(mKept, __shfl_xor(mKept, off, 16));
    }

    float e[10], s = 0.f, s2 = 0.f;
    #pragma unroll
    for (int t = 0; t < 9; ++t) {
        e[t] = __expf(x[t] - mAll);
        s  += e[t];
        s2 += e[t] * e[t];
    }
    e[9] = (q <= 6) ? __expf(x[9] - mAll) : 0.f;
    s += e[9];
    if (q <= 5) s2 += e[9] * e[9];            // exclude class 150 from |p|^2

    #pragma unroll
    for (int off = 1; off < 16; off <<= 1) {
        s  += __shfl_xor(s,  off, 16);
        s2 += __shfl_xor(s2, off, 16);
    }

    const float inv = rcpf(s);
    const float pm  = __expf(mKept - mAll) * inv;   // max kept prob
    const float nn  = s2 * inv * inv;               // sum of kept p^2

    // swizzled store
    __bf16* dstT = (set == 0 ? entP : (set == 1 ? rsP : roP));
    const int g  = i >> 4, ir = i & 15;
    __bf16* dst = dstT + ((size_t)b * 32 + g) * GRP_ELEMS + ir * 8 + (q & 7);
    const int qh = q >> 3;
    #pragma unroll
    for (int t = 0; t < 9; ++t)
        dst[(2 * t + qh) * 128] = (__bf16)(e[t] * inv);
    // t=9: kb=18+qh covers j=144..159; real only for j<=149 (q<=5), else 0
    dst[(18 + qh) * 128] = (q <= 5) ? (__bf16)(e[9] * inv) : (__bf16)0.f;

    if (q == 0) {
        const float hh = tsz[b * 2 + 0];
        const float ww = tsz[b * 2 + 1];
        if (set == 0) {
            const float* bb = boxes + (size_t)rowIdx * 4;
            const float cx = bb[0], cy = bb[1], bw = bb[2], bh = bb[3];
            const float X0 = (cx - 0.5f * bw) * ww, Y0 = (cy - 0.5f * bh) * hh;
            const float X1 = (cx + 0.5f * bw) * ww, Y1 = (cy + 0.5f * bh) * hh;
            float* A = entAux + (size_t)rowIdx * EAF;
            A[0] = pm;
            A[1] = 0.5f * (X0 + X1);
            A[2] = 0.5f * (Y0 + Y1);
            A[3] = nn;
            A[4] = X0; A[5] = Y0; A[6] = X1; A[7] = Y1;
            A[8] = (X1 - X0) * (Y1 - Y0);
        } else if (set == 1) {
            const float* bb = rs_box  + (size_t)rowIdx * 4;
            const float* vv = rel_vec + (size_t)rowIdx * 4;
            const float cx = bb[0], cy = bb[1], bw = bb[2], bh = bb[3];
            float* A = relAux + (size_t)rowIdx * RAF;
            const float X0 = (cx - 0.5f * bw) * ww, Y0 = (cy - 0.5f * bh) * hh;
            const float X1 = (cx + 0.5f * bw) * ww, Y1 = (cy + 0.5f * bh) * hh;
            A[0] = X0; A[1] = Y0; A[2] = X1; A[3] = Y1;
            A[8]  = vv[0] * ww; A[9]  = vv[1] * hh;
            A[10] = vv[2] * ww; A[11] = vv[3] * hh;
            A[12] = nn;
            A[14] = (X1 - X0) * (Y1 - Y0);
        } else {
            const float* bb = ro_box + (size_t)rowIdx * 4;
            const float cx = bb[0], cy = bb[1], bw = bb[2], bh = bb[3];
            float* A = relAux + (size_t)rowIdx * RAF;
            const float X0 = (cx - 0.5f * bw) * ww, Y0 = (cy - 0.5f * bh) * hh;
            const float X1 = (cx + 0.5f * bw) * ww, Y1 = (cy + 0.5f * bh) * hh;
            A[4] = X0; A[5] = Y0; A[6] = X1; A[7] = Y1;
            A[13] = nn;
            A[15] = (X1 - X0) * (Y1 - Y0);
        }
    }
}

// ---------------------------------------------------------------------------
// Epilogue, templated on FULL (no bounds checks for fully-interior tiles).
// ---------------------------------------------------------------------------
template <bool FULL>
__device__ __forceinline__ void epilogue(
    const float (*eA)[EAF], const float (*rA)[RAF],
    const f32x4* accS, const f32x4* accO,
    int lr, int kq, int wv, int b, int e0T, int r0T,
    float* __restrict__ outS, float* __restrict__ outO)
{
    f32x4 ev0[4], ev1[4];
    float eArea[4];
    #pragma unroll
    for (int et = 0; et < 4; ++et) {
        const float* ep = eA[et * 16 + lr];
        ev0[et] = *(const f32x4*)(ep);       // score, cx, cy, n2
        ev1[et] = *(const f32x4*)(ep + 4);   // x0, y0, x1, y1
        eArea[et] = ep[8];
    }

    const unsigned baseR0 = ((unsigned)b * NPT + (unsigned)(r0T + wv * 16 + kq * 4)) * NPT;
    const unsigned eBase  = (unsigned)(e0T + lr);

    #pragma unroll
    for (int reg = 0; reg < 4; ++reg) {
        const int rIdx = wv * 16 + kq * 4 + reg;
        const bool rOK = FULL || (r0T + rIdx < NPT);
        const float* rp = rA[rIdx];
        const f32x4 rsB = *(const f32x4*)(rp);
        const f32x4 roB = *(const f32x4*)(rp + 4);
        const f32x4 vv  = *(const f32x4*)(rp + 8);
        const f32x4 rn  = *(const f32x4*)(rp + 12);
        const unsigned rowOff = baseR0 + (unsigned)reg * NPT;

        #pragma unroll
        for (int et = 0; et < 4; ++et) {
            const float score = ev0[et][0], ecx = ev0[et][1], ecy = ev0[et][2], en2 = ev0[et][3];
            const float ex0 = ev1[et][0], ey0 = ev1[et][1], ex1 = ev1[et][2], ey1 = ev1[et][3];
            const float aE = eArea[et];

            const float iwS = fmaxf(fminf(ex1, rsB[2]) - fmaxf(ex0, rsB[0]), 0.f);
            const float ihS = fmaxf(fminf(ey1, rsB[3]) - fmaxf(ey0, rsB[1]), 0.f);
            const float inS = iwS * ihS;
            const float unS = aE + rn[2] - inS;
            const float aCS = (fmaxf(ex1, rsB[2]) - fminf(ex0, rsB[0]))
                            * (fmaxf(ey1, rsB[3]) - fminf(ey0, rsB[1]));
            const float gS  = fmaxf(fmaf(inS, rcpf(unS), fmaf(unS, rcpf(aCS), -1.f)), 0.f);

            const float iwO = fmaxf(fminf(ex1, roB[2]) - fmaxf(ex0, roB[0]), 0.f);
            const float ihO = fmaxf(fminf(ey1, roB[3]) - fmaxf(ey0, roB[1]), 0.f);
            const float inO = iwO * ihO;
            const float unO = aE + rn[3] - inO;
            const float aCO = (fmaxf(ex1, roB[2]) - fminf(ex0, roB[0]))
                            * (fmaxf(ey1, roB[3]) - fminf(ey0, roB[1]));
            const float gO  = fmaxf(fmaf(inO, rcpf(unO), fmaf(unO, rcpf(aCO), -1.f)), 0.f);

            const float d2s = fmaxf(fmaf(-2.f, accS[et][reg], rn[0] + en2), 1e-12f);
            const float d2o = fmaxf(fmaf(-2.f, accO[et][reg], rn[1] + en2), 1e-12f);
            const float dS  = d2s * rsqf(d2s);
            const float dO  = d2o * rsqf(d2o);
            const float distS = fabsf(vv[0] - ecx) + fabsf(vv[1] - ecy);
            const float distO = fabsf(vv[2] - ecx) + fabsf(vv[3] - ecy);
            const float qS = rcpf((distS + 1.f) * (dS + 1.f));
            const float qO = rcpf((distO + 1.f) * (dO + 1.f));

            const float vS = score * qS * gS;
            const float vO = score * qO * gO;

            const unsigned o = rowOff + eBase + (unsigned)(et * 16);
            if (FULL || (rOK && (int)(eBase + et * 16) < NPT)) {
                outS[o] = vS;
                outO[o] = vO;
            }
        }
    }
}

// ---------------------------------------------------------------------------
// Kernel 2: 64r x 64e tile per block; wave wv owns rows [r0T+wv*16, +16).
// blockIdx.x = image (XCD = img%8 under round-robin dispatch -> per-XCD
// prob working set = 8 images, L2-resident). Fragment loads are contiguous
// 1 KB per wave thanks to the swizzled layout.
// ---------------------------------------------------------------------------
extern "C" __global__ void __launch_bounds__(256, 4)
k_main(const __bf16* __restrict__ entP, const __bf16* __restrict__ rsP,
       const __bf16* __restrict__ roP, const float* __restrict__ eAuxG,
       const float* __restrict__ rAuxG,
       float* __restrict__ outS, float* __restrict__ outO)
{
    __shared__ __align__(16) float eA[64][EAF];
    __shared__ __align__(16) float rA[64][RAF];

    const int tid = threadIdx.x;
    const int b   = blockIdx.x;
    const int e0T = (blockIdx.y & 7) * 64;
    const int r0T = (blockIdx.y >> 3) * 64;

    {
        const float4 z = {0.f, 0.f, 0.f, 0.f};
        for (int t = tid; t < 64 * (EAF / 4); t += 256) {
            const int e = t / (EAF / 4), qq = t % (EAF / 4);
            const int ge = e0T + e;
            ((float4*)eA[e])[qq] = (ge < NPT)
                ? ((const float4*)(eAuxG + ((size_t)b * NPT + ge) * EAF))[qq] : z;
        }
        for (int t = tid; t < 64 * (RAF / 4); t += 256) {
            const int r = t / (RAF / 4), qq = t % (RAF / 4);
            const int gr = r0T + r;
            ((float4*)rA[r])[qq] = (gr < NPT)
                ? ((const float4*)(rAuxG + ((size_t)b * NPT + gr) * RAF))[qq] : z;
        }
    }
    __syncthreads();

    const int wv   = tid >> 6;
    const int lane = tid & 63;
    const int lr   = lane & 15;
    const int kq   = lane >> 4;

    const int gR = (r0T >> 4) + wv;          // rel row-group for this wave
    const int gE = (e0T >> 4);               // first ent row-group
    const __bf16* rsBase = rsP  + ((size_t)b * 32 + gR) * GRP_ELEMS + lr * 8;
    const __bf16* roBase = roP  + ((size_t)b * 32 + gR) * GRP_ELEMS + lr * 8;
    const __bf16* enBase = entP + ((size_t)b * 32 + gE) * GRP_ELEMS + lr * 8;

    f32x4 accS[4] = {{0,0,0,0},{0,0,0,0},{0,0,0,0},{0,0,0,0}};
    f32x4 accO[4] = {{0,0,0,0},{0,0,0,0},{0,0,0,0},{0,0,0,0}};

    #pragma unroll
    for (int ks = 0; ks < 5; ++ks) {
        const int kOff = (ks * 4 + kq) * 128;
        const bf16x8 ars = *(const bf16x8*)(rsBase + kOff);
        const bf16x8 aro = *(const bf16x8*)(roBase + kOff);
        #pragma unroll
        for (int et = 0; et < 4; ++et) {
            const bf16x8 be = *(const bf16x8*)(enBase + et * GRP_ELEMS + kOff);
            accS[et] = __builtin_amdgcn_mfma_f32_16x16x32_bf16(ars, be, accS[et], 0, 0, 0);
            accO[et] = __builtin_amdgcn_mfma_f32_16x16x32_bf16(aro, be, accO[et], 0, 0, 0);
        }
    }

    if (e0T + 64 <= NPT && r0T + 64 <= NPT) {
        epilogue<true >(eA, rA, accS, accO, lr, kq, wv, b, e0T, r0T, outS, outO);
    } else {
        epilogue<false>(eA, rA, accS, accO, lr, kq, wv, b, e0T, r0T, outS, outO);
    }
}

// ---------------------------------------------------------------------------
extern "C" void kernel_launch(void* const* d_in, const int* in_sizes, int n_in,
                              void* d_out, int out_size, void* d_ws, size_t ws_size,
                              hipStream_t stream)
{
    const float* boxes      = (const float*)d_in[0];
    const float* ent_logits = (const float*)d_in[1];
    const float* ro_logits  = (const float*)d_in[2];
    const float* rs_logits  = (const float*)d_in[3];
    const float* ro_box     = (const float*)d_in[4];
    const float* rs_box     = (const float*)d_in[5];
    const float* rel_vec    = (const float*)d_in[6];
    const float* tsz        = (const float*)d_in[7];

    __bf16* entP = (__bf16*)d_ws;
    __bf16* rsP  = entP + PROB_ELEMS;
    __bf16* roP  = rsP  + PROB_ELEMS;
    float*  eAux = (float*)(roP + PROB_ELEMS);
    float*  rAux = eAux + (size_t)NB * NPT * EAF;

    float* outS = (float*)d_out;
    float* outO = outS + (size_t)NB * NPT * NPT;

    hipLaunchKernelGGL(k_pre, dim3(6000), dim3(256), 0, stream,
                       boxes, ent_logits, ro_logits, rs_logits,
                       ro_box, rs_box, rel_vec, tsz,
                       entP, rsP, roP, eAux, rAux);

    hipLaunchKernelGGL(k_main, dim3(64, 64), dim3(256), 0, stream,
                       entP, rsP, roP, eAux, rAux, outS, outO);
}